// Round 1
// baseline (544.323 us; speedup 1.0000x reference)
//
#include <hip/hip_runtime.h>

#define H 64

// ---------------------------------------------------------------------------
// Kernel 1: one wave (64 lanes) per node.
//   lane h loads x[n][h]; shuffle-reduce dot products with w_i / w_j.
//   Folds in the self-loop: denom[n] = w_self, out[n][:] = w_self * x[n][:].
//   This also serves as the initializer for denom/out (harness poisons 0xAA).
// ---------------------------------------------------------------------------
__global__ void gat_node_kernel(const float* __restrict__ x,
                                const float* __restrict__ w_i,
                                const float* __restrict__ w_j,
                                float* __restrict__ s_i,
                                float* __restrict__ s_j,
                                float* __restrict__ denom,
                                float* __restrict__ out,
                                int n) {
    int wave = (blockIdx.x * blockDim.x + threadIdx.x) >> 6;
    int lane = threadIdx.x & 63;
    if (wave >= n) return;

    float v = x[(long long)wave * H + lane];
    float a = v * w_i[lane];
    float b = v * w_j[lane];
    // 64-lane butterfly reduce
    #pragma unroll
    for (int off = 32; off > 0; off >>= 1) {
        a += __shfl_down(a, off, 64);
        b += __shfl_down(b, off, 64);
    }
    a = __shfl(a, 0, 64);
    b = __shfl(b, 0, 64);
    if (lane == 0) {
        s_i[wave] = a;
        s_j[wave] = b;
    }
    // self-loop edge (n,n): e = lrelu(s_i[n] + s_j[n])
    float e = a + b;
    e = (e >= 0.f) ? e : 0.01f * e;
    float w = __expf(e);
    if (lane == 0) denom[wave] = w;
    out[(long long)wave * H + lane] = w * v;
}

// ---------------------------------------------------------------------------
// Kernel 2: one wave per edge.
//   w = exp(lrelu(s_i[dst] + s_j[src]))
//   lane h: atomicAdd(out[dst][h], w * x[src][h])   (coalesced 64-lane row)
//   lane 0: atomicAdd(denom[dst], w)
// ---------------------------------------------------------------------------
__global__ void gat_edge_kernel(const float* __restrict__ x,
                                const int* __restrict__ src,
                                const int* __restrict__ dst,
                                const float* __restrict__ s_i,
                                const float* __restrict__ s_j,
                                float* __restrict__ denom,
                                float* __restrict__ out,
                                int e_cnt) {
    int wave = (blockIdx.x * blockDim.x + threadIdx.x) >> 6;
    int lane = threadIdx.x & 63;
    if (wave >= e_cnt) return;

    int s = src[wave];
    int d = dst[wave];
    float e = s_i[d] + s_j[s];
    e = (e >= 0.f) ? e : 0.01f * e;
    float w = __expf(e);
    if (lane == 0) atomicAdd(denom + d, w);
    float v = x[(long long)s * H + lane];
    atomicAdd(out + (long long)d * H + lane, w * v);
}

// ---------------------------------------------------------------------------
// Kernel 3: out = relu(out / denom[node]) elementwise, coalesced.
// ---------------------------------------------------------------------------
__global__ void gat_final_kernel(float* __restrict__ out,
                                 const float* __restrict__ denom,
                                 int total) {
    int i = blockIdx.x * blockDim.x + threadIdx.x;
    if (i >= total) return;
    float v = out[i] / denom[i >> 6];
    out[i] = (v > 0.f) ? v : 0.f;
}

extern "C" void kernel_launch(void* const* d_in, const int* in_sizes, int n_in,
                              void* d_out, int out_size, void* d_ws, size_t ws_size,
                              hipStream_t stream) {
    const float* x    = (const float*)d_in[0];
    const int*   edge = (const int*)  d_in[1];
    const float* w_i  = (const float*)d_in[2];
    const float* w_j  = (const float*)d_in[3];

    int n     = in_sizes[0] / H;   // 100000 nodes
    int e_cnt = in_sizes[1] / 2;   // 1600000 edges

    float* out   = (float*)d_out;
    float* s_i   = (float*)d_ws;        // n floats
    float* s_j   = s_i + n;             // n floats
    float* denom = s_j + n;             // n floats

    const int BLK = 256;  // 4 waves/block

    // node pass: n waves
    long long node_threads = (long long)n * 64;
    gat_node_kernel<<<(unsigned)((node_threads + BLK - 1) / BLK), BLK, 0, stream>>>(
        x, w_i, w_j, s_i, s_j, denom, out, n);

    // edge pass: e_cnt waves
    long long edge_threads = (long long)e_cnt * 64;
    gat_edge_kernel<<<(unsigned)((edge_threads + BLK - 1) / BLK), BLK, 0, stream>>>(
        x, edge, edge + e_cnt, s_i, s_j, denom, out, e_cnt);

    // finalize
    int total = n * H;
    gat_final_kernel<<<(total + BLK - 1) / BLK, BLK, 0, stream>>>(out, denom, total);
}

// Round 2
// 353.429 us; speedup vs baseline: 1.5401x; 1.5401x over previous
//
#include <hip/hip_runtime.h>

#define H 64
#define SCAN_BLK 1024

// ws layout (floats/ints, n = 100000, e = 1600000):
//   s_i       : n floats
//   s_j       : n floats
//   count     : n ints      (in-degree histogram, zeroed by node kernel)
//   row_start : n ints      (CSR offsets, exclusive scan of count)
//   cur       : n ints      (atomic scatter cursor, init = row_start)
//   blocksum  : 128 ints    (scan partials)
//   csr       : e int2      ({src, w-as-bits} pairs grouped by dst)

// ---------------------------------------------------------------------------
// Kernel 1: one wave per node — s_i[n], s_j[n] via shuffle reduce; zero count.
// ---------------------------------------------------------------------------
__global__ void gat_node_kernel(const float* __restrict__ x,
                                const float* __restrict__ w_i,
                                const float* __restrict__ w_j,
                                float* __restrict__ s_i,
                                float* __restrict__ s_j,
                                int* __restrict__ count,
                                int n) {
    int wave = (blockIdx.x * blockDim.x + threadIdx.x) >> 6;
    int lane = threadIdx.x & 63;
    if (wave >= n) return;

    float v = x[(long long)wave * H + lane];
    float a = v * w_i[lane];
    float b = v * w_j[lane];
    #pragma unroll
    for (int off = 32; off > 0; off >>= 1) {
        a += __shfl_down(a, off, 64);
        b += __shfl_down(b, off, 64);
    }
    if (lane == 0) {
        s_i[wave] = a;
        s_j[wave] = b;
        count[wave] = 0;
    }
}

// ---------------------------------------------------------------------------
// Kernel 2: in-degree histogram over dst.
// ---------------------------------------------------------------------------
__global__ void gat_hist_kernel(const int* __restrict__ dst,
                                int* __restrict__ count, int e_cnt) {
    int i = blockIdx.x * blockDim.x + threadIdx.x;
    if (i < e_cnt) atomicAdd(&count[dst[i]], 1);
}

// ---------------------------------------------------------------------------
// Scan pass 1: per-block exclusive scan of count -> row_start; block sums out.
// ---------------------------------------------------------------------------
__global__ void scan1_kernel(const int* __restrict__ count,
                             int* __restrict__ row_start,
                             int* __restrict__ blocksum, int n) {
    __shared__ int sm[SCAN_BLK];
    int tid = threadIdx.x;
    int i = blockIdx.x * SCAN_BLK + tid;
    int c = (i < n) ? count[i] : 0;
    sm[tid] = c;
    __syncthreads();
    for (int off = 1; off < SCAN_BLK; off <<= 1) {
        int t = (tid >= off) ? sm[tid - off] : 0;
        __syncthreads();
        sm[tid] += t;
        __syncthreads();
    }
    if (i < n) row_start[i] = sm[tid] - c;           // exclusive
    if (tid == SCAN_BLK - 1) blocksum[blockIdx.x] = sm[tid];
}

// ---------------------------------------------------------------------------
// Scan pass 2: single block, exclusive scan of block sums (nb <= 128).
// ---------------------------------------------------------------------------
__global__ void scan2_kernel(int* __restrict__ blocksum, int nb) {
    __shared__ int sm[128];
    int tid = threadIdx.x;
    int c = (tid < nb) ? blocksum[tid] : 0;
    sm[tid] = c;
    __syncthreads();
    for (int off = 1; off < 128; off <<= 1) {
        int t = (tid >= off) ? sm[tid - off] : 0;
        __syncthreads();
        sm[tid] += t;
        __syncthreads();
    }
    if (tid < nb) blocksum[tid] = sm[tid] - c;       // exclusive
}

// ---------------------------------------------------------------------------
// Scan pass 3: add block offsets; init scatter cursor.
// ---------------------------------------------------------------------------
__global__ void scan3_kernel(int* __restrict__ row_start,
                             const int* __restrict__ blocksum,
                             int* __restrict__ cur, int n) {
    int i = blockIdx.x * blockDim.x + threadIdx.x;
    if (i >= n) return;
    int rs = row_start[i] + blocksum[i >> 10];
    row_start[i] = rs;
    cur[i] = rs;
}

// ---------------------------------------------------------------------------
// Kernel 3: scatter edges into CSR slots, precompute softmax weight w.
// ---------------------------------------------------------------------------
__global__ void gat_scatter_kernel(const int* __restrict__ src,
                                   const int* __restrict__ dst,
                                   const float* __restrict__ s_i,
                                   const float* __restrict__ s_j,
                                   int* __restrict__ cur,
                                   int2* __restrict__ csr, int e_cnt) {
    int i = blockIdx.x * blockDim.x + threadIdx.x;
    if (i >= e_cnt) return;
    int s = src[i];
    int d = dst[i];
    float e = s_i[d] + s_j[s];
    e = (e >= 0.f) ? e : 0.01f * e;
    float w = __expf(e);
    int pos = atomicAdd(&cur[d], 1);
    csr[pos] = make_int2(s, __float_as_int(w));
}

// ---------------------------------------------------------------------------
// Kernel 4: one wave per node — gather-reduce incoming edges, no atomics.
//   Batch 64 (src,w) pairs coalesced, shuffle-broadcast, accumulate in regs.
// ---------------------------------------------------------------------------
__global__ void gat_aggregate_kernel(const float* __restrict__ x,
                                     const float* __restrict__ s_i,
                                     const float* __restrict__ s_j,
                                     const int* __restrict__ row_start,
                                     const int* __restrict__ count,
                                     const int2* __restrict__ csr,
                                     float* __restrict__ out, int n) {
    int wave = (blockIdx.x * blockDim.x + threadIdx.x) >> 6;
    int lane = threadIdx.x & 63;
    if (wave >= n) return;

    // self-loop
    float e0 = s_i[wave] + s_j[wave];
    e0 = (e0 >= 0.f) ? e0 : 0.01f * e0;
    float wself = __expf(e0);
    float acc = wself * x[(long long)wave * H + lane];
    float den = wself;

    int start = row_start[wave];
    int cnt = count[wave];
    for (int base = 0; base < cnt; base += 64) {
        int rem = cnt - base;
        int2 pr = make_int2(0, 0);
        if (lane < rem) pr = csr[start + base + lane];
        int m = (rem < 64) ? rem : 64;
        for (int k = 0; k < m; ++k) {
            int   s = __shfl(pr.x, k, 64);
            float w = __shfl(__int_as_float(pr.y), k, 64);
            den += w;
            acc += w * x[(long long)s * H + lane];
        }
    }
    float v = acc / den;
    out[(long long)wave * H + lane] = (v > 0.f) ? v : 0.f;
}

extern "C" void kernel_launch(void* const* d_in, const int* in_sizes, int n_in,
                              void* d_out, int out_size, void* d_ws, size_t ws_size,
                              hipStream_t stream) {
    const float* x    = (const float*)d_in[0];
    const int*   edge = (const int*)  d_in[1];
    const float* w_i  = (const float*)d_in[2];
    const float* w_j  = (const float*)d_in[3];

    int n     = in_sizes[0] / H;   // 100000
    int e_cnt = in_sizes[1] / 2;   // 1600000
    const int* src = edge;
    const int* dst = edge + e_cnt;

    float* out = (float*)d_out;

    // workspace carve-up (all offsets 8B-aligned)
    char* ws = (char*)d_ws;
    float* s_i       = (float*)ws;                 ws += (size_t)n * 4;
    float* s_j       = (float*)ws;                 ws += (size_t)n * 4;
    int*   count     = (int*)ws;                   ws += (size_t)n * 4;
    int*   row_start = (int*)ws;                   ws += (size_t)n * 4;
    int*   cur       = (int*)ws;                   ws += (size_t)n * 4;
    int*   blocksum  = (int*)ws;                   ws += 128 * 4;
    int2*  csr       = (int2*)ws;

    const int BLK = 256;
    int nb = (n + SCAN_BLK - 1) / SCAN_BLK;        // 98 blocks

    long long node_threads = (long long)n * 64;
    gat_node_kernel<<<(unsigned)((node_threads + BLK - 1) / BLK), BLK, 0, stream>>>(
        x, w_i, w_j, s_i, s_j, count, n);

    gat_hist_kernel<<<(e_cnt + BLK - 1) / BLK, BLK, 0, stream>>>(dst, count, e_cnt);

    scan1_kernel<<<nb, SCAN_BLK, 0, stream>>>(count, row_start, blocksum, n);
    scan2_kernel<<<1, 128, 0, stream>>>(blocksum, nb);
    scan3_kernel<<<(n + BLK - 1) / BLK, BLK, 0, stream>>>(row_start, blocksum, cur, n);

    gat_scatter_kernel<<<(e_cnt + BLK - 1) / BLK, BLK, 0, stream>>>(
        src, dst, s_i, s_j, cur, csr, e_cnt);

    gat_aggregate_kernel<<<(unsigned)((node_threads + BLK - 1) / BLK), BLK, 0, stream>>>(
        x, s_i, s_j, row_start, count, csr, out, n);
}